// Round 6
// baseline (319.360 us; speedup 1.0000x reference)
//
#include <hip/hip_runtime.h>

#define D_MODEL   768
#define TWO_D     1536
#define SEQ       1024
#define N_LOOPS   4
#define RANK      8
#define D_STATE   16
#define EPS       1e-6f
#define XIN_LD    (N_LOOPS * TWO_D)   // 6144: xin stored [SEQ][N_LOOPS][TWO_D]

typedef unsigned short u16;
typedef short s16x8 __attribute__((ext_vector_type(8)));
typedef unsigned short u16x4 __attribute__((ext_vector_type(4)));
typedef float f32x4 __attribute__((ext_vector_type(4)));

#if defined(__has_builtin)
#  if __has_builtin(__builtin_amdgcn_global_load_lds)
#    define HAS_GLL 1
#  endif
#endif
#ifndef HAS_GLL
#  define HAS_GLL 0
#endif

__device__ inline u16 f2bf(float f) {
    union { float f; unsigned u; } v; v.f = f;
    unsigned r = v.u + 0x7fffu + ((v.u >> 16) & 1u);   // RNE
    return (u16)(r >> 16);
}
__device__ inline float bf2f(u16 b) {
    union { unsigned u; float f; } v; v.u = ((unsigned)b) << 16;
    return v.f;
}

// async global->LDS, 16B per lane; lds dest must be wave-uniform base (HW adds lane*16)
__device__ inline void gll16(const u16* g, u16* l) {
#if HAS_GLL
    __builtin_amdgcn_global_load_lds(
        (__attribute__((address_space(1))) void*)(g),
        (__attribute__((address_space(3))) void*)(l), 16, 0, 0);
#else
    const int ln = threadIdx.x & 63;
    *reinterpret_cast<uint4*>(l + ln * 8) = *reinterpret_cast<const uint4*>(g);
#endif
}

// ------- prep_g: G_k[cd] = sum_s Re( (Cr+iCi) e^{ik*theta} (Br+iBi) ), k=0..3 -------
__global__ __launch_bounds__(256) void prep_g(
    const float* __restrict__ th, const float* __restrict__ Br,
    const float* __restrict__ Bi, const float* __restrict__ Cr,
    const float* __restrict__ Ci, float* __restrict__ G)
{
    int cd = blockIdx.x * 256 + threadIdx.x;
    if (cd >= TWO_D) return;
    float g0 = 0.f, g1 = 0.f, g2 = 0.f, g3 = 0.f;
    for (int s = 0; s < D_STATE; ++s) {
        int idx = cd * D_STATE + s;
        float tt = th[idx];
        float br = Br[idx], bi = Bi[idx];
        float cr = Cr[idx], ci = Ci[idx];
#pragma unroll
        for (int k = 0; k < 4; ++k) {
            float ck = cosf(k * tt), sk = sinf(k * tt);
            float er = ck * br - sk * bi;
            float ei = sk * br + ck * bi;
            float g  = cr * er - ci * ei;
            if (k == 0) g0 += g; else if (k == 1) g1 += g;
            else if (k == 2) g2 += g; else g3 += g;
        }
    }
    G[0 * TWO_D + cd] = g0; G[1 * TWO_D + cd] = g1;
    G[2 * TWO_D + cd] = g2; G[3 * TWO_D + cd] = g3;
}

// ---- prep_all: Wbf (LoRA-merged), Wst[n][m][c] = bf16(G[3-m][c]*Wout[n][c]), h0 ----
__global__ __launch_bounds__(256) void prep_all(
    const float* __restrict__ base, const float* __restrict__ lA,
    const float* __restrict__ lB,   const float* __restrict__ wout,
    const float* __restrict__ x,    const float* __restrict__ emb0,
    const float* __restrict__ G,
    u16* __restrict__ Wbf, u16* __restrict__ Wst,
    float* __restrict__ hf, u16* __restrict__ hb)
{
    const int b = blockIdx.x, t = threadIdx.x;
    if (b < 1152) {                       // W_in = bf16(base + 2*(lB@lA)), 1536x768
        int i0 = (b * 256 + t) * 4;
        int r = i0 / D_MODEL, c = i0 % D_MODEL;
        float4 a = *reinterpret_cast<const float4*>(&base[i0]);
#pragma unroll
        for (int k = 0; k < RANK; ++k) {
            float bk = 2.0f * lB[r * RANK + k];
            const float4 av = *reinterpret_cast<const float4*>(&lA[k * D_MODEL + c]);
            a.x += bk * av.x; a.y += bk * av.y; a.z += bk * av.z; a.w += bk * av.w;
        }
        u16x4 o; o.x = f2bf(a.x); o.y = f2bf(a.y); o.z = f2bf(a.z); o.w = f2bf(a.w);
        *reinterpret_cast<u16x4*>(&Wbf[i0]) = o;
    } else if (b < 5760) {                // Wst: [768][4][1536] bf16
        int i0 = ((b - 1152) * 256 + t) * 4;          // flat over 768*4*1536
        int n = i0 / (4 * TWO_D);
        int rem = i0 - n * 4 * TWO_D;
        int m = rem / TWO_D;
        int c = rem - m * TWO_D;
        const float4 w = *reinterpret_cast<const float4*>(&wout[(size_t)n * TWO_D + c]);
        const float4 g = *reinterpret_cast<const float4*>(&G[(size_t)(3 - m) * TWO_D + c]);
        u16x4 o;
        o.x = f2bf(w.x * g.x); o.y = f2bf(w.y * g.y);
        o.z = f2bf(w.z * g.z); o.w = f2bf(w.w * g.w);
        *reinterpret_cast<u16x4*>(&Wst[i0]) = o;
    } else {                              // h0 = x + emb0 (f32 + bf16), 768 blocks
        int i0 = ((b - 5760) * 256 + t) * 4;
        int d = i0 % D_MODEL;
        const float4 v = *reinterpret_cast<const float4*>(&x[i0]);
        const float4 e = *reinterpret_cast<const float4*>(&emb0[d]);
        float4 h = make_float4(v.x + e.x, v.y + e.y, v.z + e.z, v.w + e.w);
        *reinterpret_cast<float4*>(&hf[i0]) = h;
        u16x4 o; o.x = f2bf(h.x); o.y = f2bf(h.y); o.z = f2bf(h.z); o.w = f2bf(h.w);
        *reinterpret_cast<u16x4*>(&hb[i0]) = o;
    }
}

// ---------------- bf16 NT MFMA GEMM (m97-style): C[M,N] = A[M,K]*B[N,K]^T ----------------
// BM=128, BN=64, BK=64, 256 threads = 4 waves (2x2), wave tile 64x32 = 4x2 16x16 frags.
// global_load_lds staging, linear LDS [rows][64], 2 barriers per K-step.
// blockIdx.z = split-K slice (Kz per slice); f32 output offset by kz*SEQ*ldc.
template<bool OUT_BF16>
__global__ __launch_bounds__(256) void gemm_nt(
    const u16* __restrict__ A, const int lda,
    const u16* __restrict__ B, const int ldb,
    const int Kz, void* __restrict__ Cv, const int ldc)
{
    __shared__ __align__(16) u16 Al[128 * 64];
    __shared__ __align__(16) u16 Bl[64 * 64];
    const int t = threadIdx.x;
    const int bm = blockIdx.y, bn = blockIdx.x, kz = blockIdx.z;
    const int lane = t & 63, w = t >> 6;
    const int wm = w >> 1, wn = w & 1;
    const int lr = lane & 15, kg = lane >> 4;
    const int kbase = kz * Kz;

    // staging addresses: wave w stages A rows [w*32, w*32+32), B rows [w*16, w*16+16)
    const u16* Aga = A + (size_t)(bm * 128 + w * 32 + (lane >> 3)) * lda + kbase + (lane & 7) * 8;
    const u16* Bga = B + (size_t)(bn * 64  + w * 16 + (lane >> 3)) * ldb + kbase + (lane & 7) * 8;
    u16* Alp = &Al[(w * 32) * 64];     // wave-uniform LDS base; HW adds lane*16B
    u16* Blp = &Bl[(w * 16) * 64];

    f32x4 acc[4][2] = {};
    for (int k0 = 0; k0 < Kz; k0 += 64) {
#pragma unroll
        for (int q = 0; q < 4; ++q) gll16(Aga + (size_t)q * 8 * lda + k0, Alp + q * 512);
#pragma unroll
        for (int q = 0; q < 2; ++q) gll16(Bga + (size_t)q * 8 * ldb + k0, Blp + q * 512);
        __syncthreads();                 // drains vmcnt (gll) for all waves
#pragma unroll
        for (int ks = 0; ks < 2; ++ks) {
            const int co = ks * 32 + kg * 8;
            s16x8 a[4], b[2];
#pragma unroll
            for (int m = 0; m < 4; ++m)
                a[m] = *reinterpret_cast<const s16x8*>(&Al[(wm * 64 + m * 16 + lr) * 64 + co]);
#pragma unroll
            for (int n = 0; n < 2; ++n)
                b[n] = *reinterpret_cast<const s16x8*>(&Bl[(wn * 32 + n * 16 + lr) * 64 + co]);
#pragma unroll
            for (int m = 0; m < 4; ++m)
#pragma unroll
                for (int n = 0; n < 2; ++n)
                    acc[m][n] = __builtin_amdgcn_mfma_f32_16x16x32_bf16(a[m], b[n], acc[m][n], 0, 0, 0);
        }
        __syncthreads();
    }
    // C frag layout [m89]: col = lane&15, row = (lane>>4)*4 + reg
    const int row0 = bm * 128 + wm * 64 + kg * 4;
    const int col0 = bn * 64 + wn * 32 + lr;
#pragma unroll
    for (int m = 0; m < 4; ++m)
#pragma unroll
        for (int n = 0; n < 2; ++n)
#pragma unroll
            for (int r = 0; r < 4; ++r) {
                const int row = row0 + m * 16 + r;
                const int col = col0 + n * 16;
                const float v = acc[m][n][r];
                if (OUT_BF16) ((u16*)Cv)[(size_t)row * ldc + col] = f2bf(v);
                else ((float*)Cv)[(size_t)kz * SEQ * ldc + (size_t)row * ldc + col] = v;
            }
}

// ---------- fused epilogue, wave-per-row (in-place h update) ----------
__global__ __launch_bounds__(256) void norm_kernel(
    const float* __restrict__ op0, const float* __restrict__ op1,
    const float* __restrict__ hprev,
    const float* __restrict__ mw,  const float* __restrict__ lw,
    const float* __restrict__ embn,
    float* __restrict__ dstf, u16* __restrict__ dstb)
{
    const int r = blockIdx.x * 4 + (threadIdx.x >> 6);
    const int lane = threadIdx.x & 63;
    const size_t ro = (size_t)r * D_MODEL;
    float op[12], h[12];
    float ss = 0.f;
#pragma unroll
    for (int e = 0; e < 12; ++e) {
        int d = lane + e * 64;
        op[e] = op0[ro + d] + op1[ro + d];
        h[e]  = hprev[ro + d];
        ss += op[e] * op[e];
    }
#pragma unroll
    for (int off = 32; off > 0; off >>= 1) ss += __shfl_xor(ss, off, 64);
    const float rs1 = rsqrtf(ss * (1.0f / D_MODEL) + EPS);
    float tt[12];
    float ss2 = 0.f;
#pragma unroll
    for (int e = 0; e < 12; ++e) {
        int d = lane + e * 64;
        tt[e] = h[e] + op[e] * rs1 * mw[d];
        ss2 += tt[e] * tt[e];
    }
#pragma unroll
    for (int off = 32; off > 0; off >>= 1) ss2 += __shfl_xor(ss2, off, 64);
    const float rs2 = rsqrtf(ss2 * (1.0f / D_MODEL) + EPS);
#pragma unroll
    for (int e = 0; e < 12; ++e) {
        int d = lane + e * 64;
        float xo = tt[e] * rs2 * lw[d];
        if (embn != nullptr) {
            float hn = xo + embn[d];
            dstf[ro + d] = hn;
            dstb[ro + d] = f2bf(hn);
        } else {
            dstf[ro + d] = xo;
        }
    }
}

// ------------------------------------------------------------------
extern "C" void kernel_launch(void* const* d_in, const int* in_sizes, int n_in,
                              void* d_out, int out_size, void* d_ws, size_t ws_size,
                              hipStream_t stream) {
    const float* x            = (const float*)d_in[0];
    const float* in_proj_base = (const float*)d_in[1];
    const float* lora_A       = (const float*)d_in[2];
    const float* lora_B       = (const float*)d_in[3];
    const float* A_theta      = (const float*)d_in[4];
    const float* B_real       = (const float*)d_in[5];
    const float* B_imag       = (const float*)d_in[6];
    const float* C_real       = (const float*)d_in[7];
    const float* C_imag       = (const float*)d_in[8];
    const float* out_proj_w   = (const float*)d_in[9];
    const float* mixer_w      = (const float*)d_in[10];
    const float* loop_w       = (const float*)d_in[11];
    const float* step_emb     = (const float*)d_in[12];
    float* out = (float*)d_out;

    char* p = (char*)d_ws;
    u16*   Wbf    = (u16*)p;   p += (size_t)TWO_D * D_MODEL * 2;           // 2.36 MB
    u16*   Wst    = (u16*)p;   p += (size_t)D_MODEL * 4 * TWO_D * 2;       // 9.44 MB
    float* G      = (float*)p; p += (size_t)4 * TWO_D * 4;                 // 24 KB
    u16*   xin    = (u16*)p;   p += (size_t)SEQ * XIN_LD * 2;              // 12.58 MB
    float* hf     = (float*)p; p += (size_t)SEQ * D_MODEL * 4;             // 3.15 MB
    u16*   hbf    = (u16*)p;   p += (size_t)SEQ * D_MODEL * 2;             // 1.57 MB
    float* outpre = (float*)p; p += (size_t)2 * SEQ * D_MODEL * 4;         // 6.29 MB
    // total ~35.4 MB

    prep_g<<<6, 256, 0, stream>>>(A_theta, B_real, B_imag, C_real, C_imag, G);
    prep_all<<<6528, 256, 0, stream>>>(
        in_proj_base, lora_A, lora_B, out_proj_w, x, step_emb, G,
        Wbf, Wst, hf, hbf);

    for (int i = 0; i < N_LOOPS; ++i) {
        const bool last = (i == N_LOOPS - 1);
        // gemm1: xin_i = h @ W_in^T   [1024x1536, K=768]
        gemm_nt<true><<<dim3(TWO_D / 64, SEQ / 128, 1), 256, 0, stream>>>(
            hbf, D_MODEL, Wbf, D_MODEL, D_MODEL,
            (void*)(xin + (size_t)i * TWO_D), XIN_LD);
        // gemm2: outpre = [xin_0..xin_i] @ [G_i.Wout .. G_0.Wout]^T  [K=(i+1)*1536, splitK=2]
        gemm_nt<false><<<dim3(D_MODEL / 64, SEQ / 128, 2), 256, 0, stream>>>(
            xin, XIN_LD, Wst + (size_t)(3 - i) * TWO_D, XIN_LD,
            (i + 1) * D_MODEL, (void*)outpre, D_MODEL);
        norm_kernel<<<SEQ / 4, 256, 0, stream>>>(
            outpre, outpre + (size_t)SEQ * D_MODEL, hf, mixer_w, loop_w,
            last ? nullptr : (step_emb + (size_t)(i + 1) * D_MODEL),
            last ? out : hf,
            last ? nullptr : hbf);
    }
}

// Round 8
// 234.084 us; speedup vs baseline: 1.3643x; 1.3643x over previous
//
#include <hip/hip_runtime.h>

#define D_MODEL   768
#define TWO_D     1536
#define SEQ       1024
#define N_LOOPS   4
#define RANK      8
#define D_STATE   16
#define EPS       1e-6f

typedef unsigned short u16;
typedef short s16x8 __attribute__((ext_vector_type(8)));
typedef unsigned short u16x4 __attribute__((ext_vector_type(4)));
typedef float f32x4 __attribute__((ext_vector_type(4)));

#if defined(__has_builtin)
#  if __has_builtin(__builtin_amdgcn_global_load_lds)
#    define HAS_GLL 1
#  endif
#endif
#ifndef HAS_GLL
#  define HAS_GLL 0
#endif

__device__ inline u16 f2bf(float f) {
    union { float f; unsigned u; } v; v.f = f;
    unsigned r = v.u + 0x7fffu + ((v.u >> 16) & 1u);   // RNE
    return (u16)(r >> 16);
}
__device__ inline float bf2f(u16 b) {
    union { unsigned u; float f; } v; v.u = ((unsigned)b) << 16;
    return v.f;
}

// async global->LDS, 16B/lane; global addr per-lane, LDS dest wave-uniform (HW adds lane*16B)
__device__ inline void gll16(const u16* g, u16* l) {
#if HAS_GLL
    __builtin_amdgcn_global_load_lds(
        (__attribute__((address_space(1))) void*)(g),
        (__attribute__((address_space(3))) void*)(l), 16, 0, 0);
#else
    const int ln = threadIdx.x & 63;
    *reinterpret_cast<uint4*>(l + ln * 8) = *reinterpret_cast<const uint4*>(g);
#endif
}

// ---- prep_all: Wbf (LoRA-merged), Woutbf, h0, G — one launch ----
__global__ __launch_bounds__(256) void prep_all(
    const float* __restrict__ base, const float* __restrict__ lA,
    const float* __restrict__ lB,   const float* __restrict__ wout,
    const float* __restrict__ x,    const float* __restrict__ emb0,
    const float* __restrict__ th,   const float* __restrict__ Br,
    const float* __restrict__ Bi,   const float* __restrict__ Cr,
    const float* __restrict__ Ci,
    u16* __restrict__ Wbf, u16* __restrict__ Woutbf, float* __restrict__ G,
    float* __restrict__ hf, u16* __restrict__ hb)
{
    const int b = blockIdx.x, t = threadIdx.x;
    if (b < 1152) {                       // W_in = bf16(base + 2*(lB@lA)), 1536x768
        int i0 = (b * 256 + t) * 4;
        int r = i0 / D_MODEL, c = i0 % D_MODEL;
        float4 a = *reinterpret_cast<const float4*>(&base[i0]);
#pragma unroll
        for (int k = 0; k < RANK; ++k) {
            float bk = 2.0f * lB[r * RANK + k];
            const float4 av = *reinterpret_cast<const float4*>(&lA[k * D_MODEL + c]);
            a.x += bk * av.x; a.y += bk * av.y; a.z += bk * av.z; a.w += bk * av.w;
        }
        u16x4 o; o.x = f2bf(a.x); o.y = f2bf(a.y); o.z = f2bf(a.z); o.w = f2bf(a.w);
        *reinterpret_cast<u16x4*>(&Wbf[i0]) = o;
    } else if (b < 2304) {                // Wout bf16 copy
        int i0 = ((b - 1152) * 256 + t) * 4;
        const float4 v = *reinterpret_cast<const float4*>(&wout[i0]);
        u16x4 o; o.x = f2bf(v.x); o.y = f2bf(v.y); o.z = f2bf(v.z); o.w = f2bf(v.w);
        *reinterpret_cast<u16x4*>(&Woutbf[i0]) = o;
    } else if (b < 3072) {                // h0 = x + emb0 (f32 + bf16)
        int i0 = ((b - 2304) * 256 + t) * 4;
        int d = i0 % D_MODEL;
        const float4 v = *reinterpret_cast<const float4*>(&x[i0]);
        const float4 e = *reinterpret_cast<const float4*>(&emb0[d]);
        float4 h = make_float4(v.x + e.x, v.y + e.y, v.z + e.z, v.w + e.w);
        *reinterpret_cast<float4*>(&hf[i0]) = h;
        u16x4 o; o.x = f2bf(h.x); o.y = f2bf(h.y); o.z = f2bf(h.z); o.w = f2bf(h.w);
        *reinterpret_cast<u16x4*>(&hb[i0]) = o;
    } else {                              // G_k[cd] = sum_s Re(C e^{ik theta} B)
        int cd = (b - 3072) * 256 + t;
        if (cd >= TWO_D) return;
        float g0 = 0.f, g1 = 0.f, g2 = 0.f, g3 = 0.f;
        for (int s = 0; s < D_STATE; ++s) {
            int idx = cd * D_STATE + s;
            float tt = th[idx];
            float br = Br[idx], bi = Bi[idx];
            float cr = Cr[idx], ci = Ci[idx];
#pragma unroll
            for (int k = 0; k < 4; ++k) {
                float ck = cosf(k * tt), sk = sinf(k * tt);
                float er = ck * br - sk * bi;
                float ei = sk * br + ck * bi;
                float g  = cr * er - ci * ei;
                if (k == 0) g0 += g; else if (k == 1) g1 += g;
                else if (k == 2) g2 += g; else g3 += g;
            }
        }
        G[0 * TWO_D + cd] = g0; G[1 * TWO_D + cd] = g1;
        G[2 * TWO_D + cd] = g2; G[3 * TWO_D + cd] = g3;
    }
}

// ------------- bf16 NT MFMA GEMM, split-K, f32 partial out -------------
// 64x64 tile, BK=64, 256 threads = 4 waves (2x2 quadrants of 2x2 16x16 frags).
// global_load_lds staging, linear LDS [64][64]. blockIdx.z = K-slice (Kz each);
// slice kz writes f32 partial at Cp + kz*SEQ*ldc.
__global__ __launch_bounds__(256) void gemm_nt(
    const u16* __restrict__ A, const int lda,
    const u16* __restrict__ B, const int ldb,
    const int Kz, float* __restrict__ Cp, const int ldc)
{
    __shared__ __align__(16) u16 Al[64 * 64];
    __shared__ __align__(16) u16 Bl[64 * 64];
    const int t = threadIdx.x;
    const int bm = blockIdx.y, bn = blockIdx.x, kz = blockIdx.z;
    const int lane = t & 63, w = t >> 6;
    const int wr = w >> 1, wc = w & 1;
    const int lr = lane & 15, kg = lane >> 4;
    const int kbase = kz * Kz;

    // wave w stages rows [w*16, w*16+16) of both tiles; 2 gll issues each (8 rows/issue)
    const u16* Aga = A + (size_t)(bm * 64 + w * 16 + (lane >> 3)) * lda + kbase + (lane & 7) * 8;
    const u16* Bga = B + (size_t)(bn * 64 + w * 16 + (lane >> 3)) * ldb + kbase + (lane & 7) * 8;
    u16* Alp = &Al[(w * 16) * 64];      // wave-uniform LDS base
    u16* Blp = &Bl[(w * 16) * 64];

    f32x4 acc[2][2] = {};
    for (int k0 = 0; k0 < Kz; k0 += 64) {
        gll16(Aga + k0, Alp);
        gll16(Aga + (size_t)8 * lda + k0, Alp + 8 * 64);
        gll16(Bga + k0, Blp);
        gll16(Bga + (size_t)8 * ldb + k0, Blp + 8 * 64);
        __syncthreads();                 // drains vmcnt for all waves
#pragma unroll
        for (int ks = 0; ks < 2; ++ks) {
            const int co = ks * 32 + kg * 8;
            s16x8 a0 = *reinterpret_cast<const s16x8*>(&Al[(wr * 32 +      lr) * 64 + co]);
            s16x8 a1 = *reinterpret_cast<const s16x8*>(&Al[(wr * 32 + 16 + lr) * 64 + co]);
            s16x8 b0 = *reinterpret_cast<const s16x8*>(&Bl[(wc * 32 +      lr) * 64 + co]);
            s16x8 b1 = *reinterpret_cast<const s16x8*>(&Bl[(wc * 32 + 16 + lr) * 64 + co]);
            acc[0][0] = __builtin_amdgcn_mfma_f32_16x16x32_bf16(a0, b0, acc[0][0], 0, 0, 0);
            acc[0][1] = __builtin_amdgcn_mfma_f32_16x16x32_bf16(a0, b1, acc[0][1], 0, 0, 0);
            acc[1][0] = __builtin_amdgcn_mfma_f32_16x16x32_bf16(a1, b0, acc[1][0], 0, 0, 0);
            acc[1][1] = __builtin_amdgcn_mfma_f32_16x16x32_bf16(a1, b1, acc[1][1], 0, 0, 0);
        }
        __syncthreads();
    }
    // C frag layout [m89]: col = lane&15, row = (lane>>4)*4 + reg
    const int row0 = bm * 64 + wr * 32 + kg * 4;
    const int col0 = bn * 64 + wc * 32 + lr;
    float* Cz = Cp + (size_t)kz * SEQ * ldc;
#pragma unroll
    for (int m = 0; m < 2; ++m)
#pragma unroll
        for (int n = 0; n < 2; ++n)
#pragma unroll
            for (int r = 0; r < 4; ++r)
                Cz[(size_t)(row0 + m * 16 + r) * ldc + col0 + n * 16] = acc[m][n][r];
}

// --- y_kernel: combine gemm1 partials -> xin_i (bf16), y = sum_j G[i-j] ⊙ xin_j ---
__global__ __launch_bounds__(256) void y_kernel(
    const float* __restrict__ p,     // [2][SEQ][TWO_D] f32 partials of h @ W_in^T
    u16* __restrict__ xin,           // [N_LOOPS][SEQ][TWO_D]
    const float* __restrict__ G,     // [4][TWO_D]
    const int li, u16* __restrict__ y)
{
    int i4 = blockIdx.x * 256 + threadIdx.x;        // 0 .. 1024*1536/4-1
    int base = i4 * 4;
    int cd = base % TWO_D;
    const float4 v0 = *reinterpret_cast<const float4*>(&p[base]);
    const float4 v1 = *reinterpret_cast<const float4*>(&p[(size_t)SEQ * TWO_D + base]);
    float4 s = make_float4(v0.x + v1.x, v0.y + v1.y, v0.z + v1.z, v0.w + v1.w);
    u16x4 xo; xo.x = f2bf(s.x); xo.y = f2bf(s.y); xo.z = f2bf(s.z); xo.w = f2bf(s.w);
    *reinterpret_cast<u16x4*>(&xin[(size_t)li * SEQ * TWO_D + base]) = xo;
    const float4 g0 = *reinterpret_cast<const float4*>(&G[cd]);
    float s0 = g0.x * s.x, s1 = g0.y * s.y, s2 = g0.z * s.z, s3 = g0.w * s.w;
    for (int j = 0; j < li; ++j) {
        u16x4 v = *reinterpret_cast<const u16x4*>(&xin[(size_t)j * SEQ * TWO_D + base]);
        const float4 g = *reinterpret_cast<const float4*>(&G[(size_t)(li - j) * TWO_D + cd]);
        s0 += bf2f(v.x) * g.x; s1 += bf2f(v.y) * g.y;
        s2 += bf2f(v.z) * g.z; s3 += bf2f(v.w) * g.w;
    }
    u16x4 o; o.x = f2bf(s0); o.y = f2bf(s1); o.z = f2bf(s2); o.w = f2bf(s3);
    *reinterpret_cast<u16x4*>(&y[base]) = o;
}

// ---------- fused epilogue, wave-per-row: sums 4 gemm2 partials ----------
__global__ __launch_bounds__(256) void norm_kernel(
    const float* __restrict__ q,      // [4][SEQ][D_MODEL] f32 partials
    const float* __restrict__ hprev,
    const float* __restrict__ mw,  const float* __restrict__ lw,
    const float* __restrict__ embn,
    float* __restrict__ dstf, u16* __restrict__ dstb)
{
    const int r = blockIdx.x * 4 + (threadIdx.x >> 6);
    const int lane = threadIdx.x & 63;
    const size_t ro = (size_t)r * D_MODEL;
    const size_t PS = (size_t)SEQ * D_MODEL;
    float op[12], h[12];
    float ss = 0.f;
#pragma unroll
    for (int e = 0; e < 12; ++e) {
        int d = lane + e * 64;
        op[e] = (q[ro + d] + q[PS + ro + d]) + (q[2 * PS + ro + d] + q[3 * PS + ro + d]);
        h[e]  = hprev[ro + d];
        ss += op[e] * op[e];
    }
#pragma unroll
    for (int off = 32; off > 0; off >>= 1) ss += __shfl_xor(ss, off, 64);
    const float rs1 = rsqrtf(ss * (1.0f / D_MODEL) + EPS);
    float tt[12];
    float ss2 = 0.f;
#pragma unroll
    for (int e = 0; e < 12; ++e) {
        int d = lane + e * 64;
        tt[e] = h[e] + op[e] * rs1 * mw[d];
        ss2 += tt[e] * tt[e];
    }
#pragma unroll
    for (int off = 32; off > 0; off >>= 1) ss2 += __shfl_xor(ss2, off, 64);
    const float rs2 = rsqrtf(ss2 * (1.0f / D_MODEL) + EPS);
#pragma unroll
    for (int e = 0; e < 12; ++e) {
        int d = lane + e * 64;
        float xo = tt[e] * rs2 * lw[d];
        if (embn != nullptr) {
            float hn = xo + embn[d];
            dstf[ro + d] = hn;
            dstb[ro + d] = f2bf(hn);
        } else {
            dstf[ro + d] = xo;
        }
    }
}

// ------------------------------------------------------------------
extern "C" void kernel_launch(void* const* d_in, const int* in_sizes, int n_in,
                              void* d_out, int out_size, void* d_ws, size_t ws_size,
                              hipStream_t stream) {
    const float* x            = (const float*)d_in[0];
    const float* in_proj_base = (const float*)d_in[1];
    const float* lora_A       = (const float*)d_in[2];
    const float* lora_B       = (const float*)d_in[3];
    const float* A_theta      = (const float*)d_in[4];
    const float* B_real       = (const float*)d_in[5];
    const float* B_imag       = (const float*)d_in[6];
    const float* C_real       = (const float*)d_in[7];
    const float* C_imag       = (const float*)d_in[8];
    const float* out_proj_w   = (const float*)d_in[9];
    const float* mixer_w      = (const float*)d_in[10];
    const float* loop_w       = (const float*)d_in[11];
    const float* step_emb     = (const float*)d_in[12];
    float* out = (float*)d_out;

    char* p8 = (char*)d_ws;
    u16*   Wbf    = (u16*)p8;   p8 += (size_t)TWO_D * D_MODEL * 2;        // 2.36 MB
    u16*   Woutbf = (u16*)p8;   p8 += (size_t)D_MODEL * TWO_D * 2;        // 2.36 MB
    float* G      = (float*)p8; p8 += (size_t)4 * TWO_D * 4;              // 24 KB
    u16*   xin    = (u16*)p8;   p8 += (size_t)N_LOOPS * SEQ * TWO_D * 2;  // 12.58 MB
    u16*   ybf    = (u16*)p8;   p8 += (size_t)SEQ * TWO_D * 2;            // 3.15 MB
    float* hf     = (float*)p8; p8 += (size_t)SEQ * D_MODEL * 4;          // 3.15 MB
    u16*   hbf    = (u16*)p8;   p8 += (size_t)SEQ * D_MODEL * 2;          // 1.57 MB
    float* pbuf   = (float*)p8; p8 += (size_t)2 * SEQ * TWO_D * 4;        // 12.58 MB (gemm1 partials)
    float* qbuf   = (float*)p8; p8 += (size_t)4 * SEQ * D_MODEL * 4;      // 12.58 MB (gemm2 partials)
    // total ~50.3 MB

    prep_all<<<3078, 256, 0, stream>>>(
        in_proj_base, lora_A, lora_B, out_proj_w, x, step_emb,
        A_theta, B_real, B_imag, C_real, C_imag,
        Wbf, Woutbf, G, hf, hbf);

    for (int i = 0; i < N_LOOPS; ++i) {
        const bool last = (i == N_LOOPS - 1);
        // gemm1: p[kz] = h @ W_in^T slice   [M=1024,N=1536,K=768, splitK=2 -> 768 blocks]
        gemm_nt<<<dim3(TWO_D / 64, SEQ / 64, 2), 256, 0, stream>>>(
            hbf, D_MODEL, Wbf, D_MODEL, D_MODEL / 2, pbuf, TWO_D);
        // y: xin_i = bf16(p0+p1); y = sum_j G[i-j] ⊙ xin_j
        y_kernel<<<(SEQ * TWO_D / 4) / 256, 256, 0, stream>>>(pbuf, xin, G, i, ybf);
        // gemm2: q[kz] = y @ Wout^T slice   [M=1024,N=768,K=1536, splitK=4 -> 768 blocks]
        gemm_nt<<<dim3(D_MODEL / 64, SEQ / 64, 4), 256, 0, stream>>>(
            ybf, TWO_D, Woutbf, TWO_D, TWO_D / 4, qbuf, D_MODEL);
        norm_kernel<<<SEQ / 4, 256, 0, stream>>>(
            qbuf, hf, mixer_w, loop_w,
            last ? nullptr : (step_emb + (size_t)(i + 1) * D_MODEL),
            last ? out : hf,
            last ? nullptr : hbf);
    }
}